// Round 5
// baseline (693.388 us; speedup 1.0000x reference)
//
#include <hip/hip_runtime.h>

#define BB 64
#define TT 2048
#define DD 512
#define UU 32

// ---------------------------------------------------------------------------
// K1: logits[b,t,u] = sum_k x[b,t,k]*kernel[k,u] + bias[u]   (unchanged)
// ---------------------------------------------------------------------------
__global__ __launch_bounds__(256) void k1_logits(const float* __restrict__ x,
                                                 const float* __restrict__ w,
                                                 const float* __restrict__ bias,
                                                 float* __restrict__ out) {
  __shared__ float xs[256 * 34];
  __shared__ float wsh[32 * 36];
  const int tid = threadIdx.x;
  const long row0 = (long)blockIdx.x * 256;
  const int tr = tid >> 2;
  const int tc = tid & 3;
  const int ubase = tc * 8;
  const int sr = tid >> 3;
  const int sc = (tid & 7) * 4;

  float acc[4][8];
#pragma unroll
  for (int i = 0; i < 4; ++i)
#pragma unroll
    for (int j = 0; j < 8; ++j) acc[i][j] = 0.0f;

  for (int kc = 0; kc < DD; kc += 32) {
#pragma unroll
    for (int p = 0; p < 8; ++p) {
      const int r = p * 32 + sr;
      const float4 v = *(const float4*)(x + (row0 + r) * DD + kc + sc);
      *(float2*)(&xs[r * 34 + sc]) = make_float2(v.x, v.y);
      *(float2*)(&xs[r * 34 + sc + 2]) = make_float2(v.z, v.w);
    }
    {
      const int k = tid >> 3;
      const int uu4 = (tid & 7) * 4;
      const float4 v = *(const float4*)(w + (size_t)(kc + k) * UU + uu4);
      *(float4*)(&wsh[k * 36 + uu4]) = v;
    }
    __syncthreads();
#pragma unroll
    for (int k = 0; k < 32; ++k) {
      const float4 w0 = *(const float4*)(&wsh[k * 36 + ubase]);
      const float4 w1 = *(const float4*)(&wsh[k * 36 + ubase + 4]);
      const float wv[8] = {w0.x, w0.y, w0.z, w0.w, w1.x, w1.y, w1.z, w1.w};
#pragma unroll
      for (int i = 0; i < 4; ++i) {
        const float xv = xs[(tr + 64 * i) * 34 + k];
#pragma unroll
        for (int j = 0; j < 8; ++j) acc[i][j] = fmaf(xv, wv[j], acc[i][j]);
      }
    }
    __syncthreads();
  }
  float bv[8];
#pragma unroll
  for (int j = 0; j < 8; ++j) bv[j] = bias[ubase + j];
#pragma unroll
  for (int i = 0; i < 4; ++i) {
    const long row = row0 + tr + 64 * i;
    float4 o0, o1;
    o0.x = acc[i][0] + bv[0]; o0.y = acc[i][1] + bv[1];
    o0.z = acc[i][2] + bv[2]; o0.w = acc[i][3] + bv[3];
    o1.x = acc[i][4] + bv[4]; o1.y = acc[i][5] + bv[5];
    o1.z = acc[i][6] + bv[6]; o1.w = acc[i][7] + bv[7];
    *(float4*)(out + row * UU + ubase) = o0;
    *(float4*)(out + row * UU + ubase + 4) = o1;
  }
}

// ---------------------------------------------------------------------------
// K2: Viterbi forward — D/E-alternating permlane edition, 8 chains per block.
// Layout D rows = [lo,hi,lo,hi] (content col bit4*16+q), layout E rows =
// [lo,lo,hi,hi] (content col bit5*16+q... content always alpha[half*16+q]).
// D-step: sources = own row half (bit4), target colD = bit5*16+q, pairs at
// l^16 -> permlane16_swap + fmax -> layout E. E-step: sources half bit5,
// target colE = bit4*16+q, pairs at l^32 -> permlane32_swap + fmax -> D.
// Symmetric max-combines only: direction-proof, no cndmask restore.
// t odd = D-step, t even = E-step; alpha0 enters as layout D (P = row0[colE]).
// All 2047 steps run unconditionally (rows >= nw are garbage, never used).
// 512-thread blocks (8 waves = 8 chains) -> 2 waves/SIMD fill stall cycles.
// Fallback combine via ds_bpermute if permlane probes fail.
// ---------------------------------------------------------------------------
__global__ __launch_bounds__(512) void k2_forward(float* __restrict__ lb,
                                                  const float* __restrict__ trans) {
  const int tid = threadIdx.x;
  const int lane = tid & 63;
  const int b = blockIdx.x * 8 + (tid >> 6);
  const int q = lane & 15;
  const int bit4 = (lane >> 4) & 1;
  const int bit5 = (lane >> 5) & 1;
  const int colD = bit5 * 16 + q;  // D-step target/store/logit col
  const int colE = bit4 * 16 + q;  // E-step target col; also alpha0 content col

  // DPP row_ror direction probe (bound_ctrl=false here: probing raw semantics)
  const int probe = __builtin_amdgcn_update_dpp(0, q, 0x121, 0xF, 0xF, false);
  const bool dirp = (probe == ((q + 1) & 15));

  float tvD[16], tvE[16];
#pragma unroll
  for (int s = 0; s < 16; ++s) {
    const int rp = dirp ? ((q + s) & 15) : ((q - s) & 15);
    tvD[s] = trans[(bit4 * 16 + rp) * UU + colD];
    tvE[s] = trans[(bit5 * 16 + rp) * UU + colE];
  }

  float* base = lb + (size_t)b * TT * UU;
  float P = base[colE];  // alpha0 in layout D

  float bufA[16], bufB[16];

#define ROTF(S) \
  __int_as_float(__builtin_amdgcn_update_dpp(0, __float_as_int(P), 0x120 + (S), 0xF, 0xF, true))

#define K2_TREE(TV)                                                          \
    const float c0 = P + (TV)[0];                                            \
    const float c1 = ROTF(1) + (TV)[1];                                      \
    const float c2 = ROTF(2) + (TV)[2];                                      \
    const float c3 = ROTF(3) + (TV)[3];                                      \
    const float c4 = ROTF(4) + (TV)[4];                                      \
    const float c5 = ROTF(5) + (TV)[5];                                      \
    const float c6 = ROTF(6) + (TV)[6];                                      \
    const float c7 = ROTF(7) + (TV)[7];                                      \
    const float c8 = ROTF(8) + (TV)[8];                                      \
    const float c9 = ROTF(9) + (TV)[9];                                      \
    const float c10 = ROTF(10) + (TV)[10];                                   \
    const float c11 = ROTF(11) + (TV)[11];                                   \
    const float c12 = ROTF(12) + (TV)[12];                                   \
    const float c13 = ROTF(13) + (TV)[13];                                   \
    const float c14 = ROTF(14) + (TV)[14];                                   \
    const float c15 = ROTF(15) + (TV)[15];                                   \
    const float d0 = fmaxf(fmaxf(c0, c1), c2);                               \
    const float d1 = fmaxf(fmaxf(c3, c4), c5);                               \
    const float d2 = fmaxf(fmaxf(c6, c7), c8);                               \
    const float d3 = fmaxf(fmaxf(c9, c10), c11);                             \
    const float d4 = fmaxf(fmaxf(c12, c13), c14);                            \
    const float e0 = fmaxf(fmaxf(d0, d1), d2);                               \
    const float e1 = fmaxf(fmaxf(d3, d4), c15);                              \
    const float pm = fmaxf(e0, e1);

// One step: TV table, CMB combine expr (must equal max(pm, pm[l^k])), COL col.
#define K2_STEP(tval, lg, TV, CMB, COL) do {                                 \
    K2_TREE(TV)                                                              \
    P = (CMB) + (lg);                                                        \
    base[(size_t)(tval) * UU + (COL)] = P;                                   \
  } while (0)

// Full 2047-step schedule. DSTEP/ESTEP are the two combine exprs.
#define K2_LOOP(DCMB, ECMB)                                                  \
  _Pragma("unroll")                                                          \
  for (int i = 0; i < 16; ++i)                                               \
    bufA[i] = base[(size_t)(1 + i) * UU + ((i & 1) ? colE : colD)];          \
  _Pragma("unroll 1")                                                        \
  for (int tc = 1; tc <= 1985; tc += 32) {                                   \
    _Pragma("unroll")                                                        \
    for (int i = 0; i < 16; ++i)                                             \
      bufB[i] = base[(size_t)(tc + 16 + i) * UU + ((i & 1) ? colE : colD)];  \
    _Pragma("unroll")                                                        \
    for (int i = 0; i < 16; ++i) {                                           \
      if ((i & 1) == 0) K2_STEP(tc + i, bufA[i], tvD, DCMB, colD);           \
      else              K2_STEP(tc + i, bufA[i], tvE, ECMB, colE);           \
    }                                                                        \
    _Pragma("unroll")                                                        \
    for (int i = 0; i < 16; ++i)                                             \
      bufA[i] = base[(size_t)(tc + 32 + i) * UU + ((i & 1) ? colE : colD)];  \
    _Pragma("unroll")                                                        \
    for (int i = 0; i < 16; ++i) {                                           \
      if ((i & 1) == 0) K2_STEP(tc + 16 + i, bufB[i], tvD, DCMB, colD);      \
      else              K2_STEP(tc + 16 + i, bufB[i], tvE, ECMB, colE);      \
    }                                                                        \
  }                                                                          \
  _Pragma("unroll")                                                          \
  for (int i = 0; i < 16; ++i) {                                             \
    int r = 2033 + i; if (r > TT - 1) r = TT - 1;                            \
    bufB[i] = base[(size_t)r * UU + ((i & 1) ? colE : colD)];                \
  }                                                                          \
  _Pragma("unroll")                                                          \
  for (int i = 0; i < 16; ++i) {                                             \
    if ((i & 1) == 0) K2_STEP(2017 + i, bufA[i], tvD, DCMB, colD);           \
    else              K2_STEP(2017 + i, bufA[i], tvE, ECMB, colE);           \
  }                                                                          \
  _Pragma("unroll")                                                          \
  for (int i = 0; i < 15; ++i) {                                             \
    if ((i & 1) == 0) K2_STEP(2033 + i, bufB[i], tvD, DCMB, colD);           \
    else              K2_STEP(2033 + i, bufB[i], tvE, ECMB, colE);           \
  }

#if __has_builtin(__builtin_amdgcn_permlane32_swap) && __has_builtin(__builtin_amdgcn_permlane16_swap)
  typedef unsigned int v2u __attribute__((ext_vector_type(2)));
  // Probe: both outputs together must contain {x[l], x[l^k]} for every lane.
  v2u p32 = __builtin_amdgcn_permlane32_swap((unsigned)lane, (unsigned)lane, false, false);
  v2u p16 = __builtin_amdgcn_permlane16_swap((unsigned)lane, (unsigned)lane, false, false);
  const bool c32ok = ((int)p32.x == (lane ^ 32)) || ((int)p32.y == (lane ^ 32));
  const bool c16ok = ((int)p16.x == (lane ^ 16)) || ((int)p16.y == (lane ^ 16));
  const bool okSwap = (__ballot(c32ok) == ~0ull) && (__ballot(c16ok) == ~0ull);

#define CMB16P ({ v2u s_ = __builtin_amdgcn_permlane16_swap(                  \
                      __float_as_uint(pm), __float_as_uint(pm), false, false);\
                  fmaxf(__uint_as_float(s_.x), __uint_as_float(s_.y)); })
#define CMB32P ({ v2u s_ = __builtin_amdgcn_permlane32_swap(                  \
                      __float_as_uint(pm), __float_as_uint(pm), false, false);\
                  fmaxf(__uint_as_float(s_.x), __uint_as_float(s_.y)); })

  if (okSwap) {
    K2_LOOP(CMB16P, CMB32P)
    return;
  }
#endif

  // Fallback: same D/E scheme, combines via ds_bpermute.
  {
    const int idx16 = (lane ^ 16) << 2;
    const int idx32 = (lane ^ 32) << 2;
#define CMB16B fmaxf(pm, __int_as_float(__builtin_amdgcn_ds_bpermute(idx16, __float_as_int(pm))))
#define CMB32B fmaxf(pm, __int_as_float(__builtin_amdgcn_ds_bpermute(idx32, __float_as_int(pm))))
    K2_LOOP(CMB16B, CMB32B)
  }
}

// ---------------------------------------------------------------------------
// K3: backpointers, fully parallel from stored alpha rows.  (unchanged)
// ---------------------------------------------------------------------------
__global__ __launch_bounds__(256) void k3_bp(const float* __restrict__ lb,
                                             const float* __restrict__ trans,
                                             const int* __restrict__ nwords,
                                             unsigned char* __restrict__ bp) {
  __shared__ float as[129 * 32];
  __shared__ float ts[32 * 32];
  const int b = blockIdx.x >> 4;
  const int c = blockIdx.x & 15;
  const int t0 = 128 * c;
  const int tid = threadIdx.x;
  const float* base = lb + (size_t)b * TT * UU;
  const int nw = nwords[b];

  for (int idx = tid; idx < 129 * 32; idx += 256) {
    const int gidx = (t0 - 1) * 32 + idx;
    as[idx] = (gidx >= 0 && gidx < TT * UU) ? base[gidx] : 0.0f;
  }
  for (int idx = tid; idx < 1024; idx += 256) ts[idx] = trans[idx];
  __syncthreads();

  const int u = tid & 31;
  const int tg = tid >> 5;
  unsigned char* bpu = bp + ((size_t)b * 32 + u) * TT;

#pragma unroll 1
  for (int qq = 0; qq < 4; ++qq) {
    const int tl0 = tg * 16 + qq * 4;
    unsigned int pack = 0;
#pragma unroll
    for (int e = 0; e < 4; ++e) {
      const int tl = tl0 + e;
      const int t = t0 + tl;
      int idx;
      if (t >= 1 && t < nw) {
        float m = as[tl * 32 + 0] + ts[0 * 32 + u];
        idx = 0;
#pragma unroll
        for (int v = 1; v < 32; ++v) {
          const float cv = as[tl * 32 + v] + ts[v * 32 + u];
          if (cv > m) { m = cv; idx = v; }
        }
      } else {
        idx = u;
      }
      pack |= ((unsigned int)idx) << (8 * e);
    }
    *(unsigned int*)(bpu + t0 + tl0) = pack;
  }
}

// ---------------------------------------------------------------------------
// K4: backtrace + best_score. One wave per chain.  (unchanged)
// ---------------------------------------------------------------------------
__global__ __launch_bounds__(64) void k4_backtrace(const float* __restrict__ lb,
                                                   const unsigned char* __restrict__ bp,
                                                   const int* __restrict__ nwords,
                                                   int* __restrict__ pred,
                                                   float* __restrict__ score) {
  const int b = blockIdx.x;
  const int lane = threadIdx.x;
  const int u = lane & 31;
  const int h = lane >> 5;
  const int nw = nwords[b];

  const float a = lb[((size_t)b * TT + (nw - 1)) * UU + u];
  float m = a;
#pragma unroll
  for (int s = 32; s; s >>= 1) m = fmaxf(m, __shfl_xor(m, s));
  if (lane == 0) score[b] = m;
  const unsigned long long mask = __ballot(lane < 32 && a == m);
  int tag = __ffsll((unsigned long long)mask) - 1;
  tag = __builtin_amdgcn_readfirstlane(tag);

  int* predb = pred + b * TT;
  for (int p = nw - 1 + lane; p < TT; p += 64) predb[p] = tag;
  if (nw < 2) return;

  const unsigned char* bpb = bp + (size_t)b * 32 * TT;
  const int pcmax = (nw - 2) >> 6;
  const int thi_top = nw - 1;

  int wprev0 = 0;
  {
    const int toff = (pcmax + 1) * 64;
    if (toff < TT) wprev0 = *(const int*)(bpb + (size_t)u * TT + toff);
  }

  for (int pc = pcmax; pc >= 0; --pc) {
    int wreg[8];
#pragma unroll
    for (int j = 0; j < 8; ++j)
      wreg[j] = *(const int*)(bpb + (size_t)u * TT + pc * 64 + 4 * (h * 8 + j));
    const int thi = (pc == pcmax) ? thi_top : (pc * 64 + 64);
    int predv = 0;

    if (pc * 64 + 64 <= thi) {
      const int val = __builtin_amdgcn_readlane(wprev0, tag);
      tag = __builtin_amdgcn_readfirstlane(val & 0xFF);
      if (lane == 63) predv = tag;
    }
#pragma unroll
    for (int lt = 63; lt >= 1; --lt) {
      if (pc * 64 + lt <= thi) {
        const int d = lt >> 2, byte = lt & 3;
        const int hs = d >> 3, j = d & 7;
        const int val = __builtin_amdgcn_readlane(wreg[j], hs * 32 + tag);
        tag = __builtin_amdgcn_readfirstlane((val >> (8 * byte)) & 0xFF);
        if (lane == lt - 1) predv = tag;
      }
    }
    const int lim = thi - pc * 64;
    if (lane < lim) predb[pc * 64 + lane] = predv;
    wprev0 = wreg[0];
  }
}

// ---------------------------------------------------------------------------
extern "C" void kernel_launch(void* const* d_in, const int* in_sizes, int n_in,
                              void* d_out, int out_size, void* d_ws, size_t ws_size,
                              hipStream_t stream) {
  const float* x = (const float*)d_in[0];
  const int* nwords = (const int*)d_in[1];
  const float* kern = (const float*)d_in[2];
  const float* chain = (const float*)d_in[3];
  const float* bias = (const float*)d_in[4];

  float* logits = (float*)d_ws;                                        // 16 MB
  unsigned char* bp = (unsigned char*)d_ws + (size_t)BB * TT * UU * 4; // +4 MB

  int* pred = (int*)d_out;
  float* score = (float*)d_out + (size_t)BB * TT;

  k1_logits<<<dim3(512), dim3(256), 0, stream>>>(x, kern, bias, logits);
  k2_forward<<<dim3(8), dim3(512), 0, stream>>>(logits, chain);
  k3_bp<<<dim3(BB * 16), dim3(256), 0, stream>>>(logits, chain, nwords, bp);
  k4_backtrace<<<dim3(BB), dim3(64), 0, stream>>>(logits, bp, nwords, pred, score);
}